// Round 8
// baseline (134.907 us; speedup 1.0000x reference)
//
#include <hip/hip_runtime.h>
#include <math.h>

#define N_A   1024
#define HDIM  128
#define DIN   172
#define E_CNT 256
#define LP    72      // LDS pitch (bf16) for 64-wide GEMM tiles
#define LPA   136     // LDS pitch (bf16) for 128-wide xn tile

typedef __attribute__((ext_vector_type(8))) short bf16x8;
typedef __attribute__((ext_vector_type(4))) float f32x4;

__device__ __forceinline__ unsigned short f2bf(float x) {
    unsigned int u = __float_as_uint(x);
    unsigned int r = (u + 0x7fffu + ((u >> 16) & 1u)) >> 16;
    return (unsigned short)r;
}

// Gauss-Legendre nodes/weights mapped to [0,1] (tau=1)
__constant__ float c_t[8] = {
    0.4082826787521751f, 0.2372337950418355f, 0.10166676129318665f, 0.019855071751231843f,
    0.5917173212478249f, 0.7627662049581645f, 0.8983332387068134f, 0.9801449282487682f};
__constant__ float c_w[8] = {
    0.181341891689181f, 0.15685332293894365f, 0.11119051722668725f, 0.05061426814518815f,
    0.181341891689181f, 0.15685332293894365f, 0.11119051722668725f, 0.05061426814518815f};

// ---------------------------------------------------------------------------
// conv_all: all fp32 -> bf16 conversions / transposes
//  blocks [0,2048):    L,dL -> Lb,dLb           (4 elems/thread)
//  blocks [2048,2816): x_in (x_sub|neigh|pad) -> Xb [1024][192]
//  blocks [2816,2912): W_tune^T zero-padded   -> WtT [128][192]
//  blocks [2912,3040): W_B1^T, W_B2^T         -> WB1T/WB2T [128][128]
// ---------------------------------------------------------------------------
__global__ __launch_bounds__(256)
void conv_all(const float* __restrict__ L, const float* __restrict__ dL,
              const float* __restrict__ x_sub, const float* __restrict__ names,
              const int* __restrict__ src, const int* __restrict__ dst,
              const float* __restrict__ W_tune, const float* __restrict__ W_B1,
              const float* __restrict__ W_B2,
              unsigned short* __restrict__ Lb, unsigned short* __restrict__ dLb,
              unsigned short* __restrict__ Xb, unsigned short* __restrict__ WtT,
              unsigned short* __restrict__ WB1T, unsigned short* __restrict__ WB2T)
{
    const int b = blockIdx.x, tid = threadIdx.x;
    if (b < 2048) {
        const int t = b * 256 + tid;
        const float* s = (t < 262144) ? L : dL;
        unsigned short* d = (t < 262144) ? Lb : dLb;
        const int q = (t < 262144) ? t : t - 262144;
        float4 v = *(const float4*)(s + (size_t)q * 4);
        ushort4 o;
        o.x = f2bf(v.x); o.y = f2bf(v.y); o.z = f2bf(v.z); o.w = f2bf(v.w);
        *(ushort4*)(d + (size_t)q * 4) = o;
    } else if (b < 2816) {
        const int t = (b - 2048) * 256 + tid;        // 0..196607
        const int i = t / 192, k = t - i * 192;
        float val = 0.f;
        if (k < DIN) val = x_sub[(size_t)i * DIN + k];
        else if (k == DIN) {
            if (i < E_CNT)          val = names[src[i]];
            else if (i < 2 * E_CNT) val = names[dst[i - E_CNT]];
        } else if (k == DIN + 1) {
            if (i < E_CNT)          val = names[dst[i]];
            else if (i < 2 * E_CNT) val = names[src[i - E_CNT]];
        }
        Xb[t] = f2bf(val);
    } else if (b < 2912) {
        const int t = (b - 2816) * 256 + tid;        // 0..24575
        const int j = t / 192, k = t - j * 192;
        WtT[t] = (k < DIN + 2) ? f2bf(W_tune[k * HDIM + j]) : (unsigned short)0;
    } else {
        const int t = (b - 2912) * 256 + tid;        // 0..32767
        const int half = t >> 14, tt = t & 16383;
        const int j = tt >> 7, k = tt & 127;
        (half ? WB2T : WB1T)[tt] = f2bf((half ? W_B2 : W_B1)[k * HDIM + j]);
    }
}

// ---------------------------------------------------------------------------
// single-A 64x64 MFMA core (A,B K-contiguous, row stride baked into ag/bg)
// ---------------------------------------------------------------------------
__device__ __forceinline__ void core_sa(
    const unsigned short* __restrict__ ag, const unsigned short* __restrict__ bg,
    unsigned short* As, unsigned short* Bs, int klen,
    int srow, int skc, int wrow, int wcol, int fr, int fk, f32x4 (&acc)[2][2])
{
    bf16x8 pa0 = *(const bf16x8*)ag, pa1 = *(const bf16x8*)(ag + 8);
    bf16x8 pb0 = *(const bf16x8*)bg, pb1 = *(const bf16x8*)(bg + 8);
    for (int k0 = 0; k0 < klen; k0 += 64) {
        __syncthreads();
        *(bf16x8*)&As[srow * LP + skc] = pa0; *(bf16x8*)&As[srow * LP + skc + 8] = pa1;
        *(bf16x8*)&Bs[srow * LP + skc] = pb0; *(bf16x8*)&Bs[srow * LP + skc + 8] = pb1;
        __syncthreads();
        if (k0 + 64 < klen) {
            pa0 = *(const bf16x8*)(ag + k0 + 64); pa1 = *(const bf16x8*)(ag + k0 + 72);
            pb0 = *(const bf16x8*)(bg + k0 + 64); pb1 = *(const bf16x8*)(bg + k0 + 72);
        }
        #pragma unroll
        for (int h = 0; h < 2; ++h) {
            const int ko = h * 32 + fk;
            bf16x8 a0 = *(const bf16x8*)&As[(wrow + fr) * LP + ko];
            bf16x8 a1 = *(const bf16x8*)&As[(wrow + 16 + fr) * LP + ko];
            bf16x8 b0 = *(const bf16x8*)&Bs[(wcol + fr) * LP + ko];
            bf16x8 b1 = *(const bf16x8*)&Bs[(wcol + 16 + fr) * LP + ko];
            acc[0][0] = __builtin_amdgcn_mfma_f32_16x16x32_bf16(a0, b0, acc[0][0], 0, 0, 0);
            acc[0][1] = __builtin_amdgcn_mfma_f32_16x16x32_bf16(a0, b1, acc[0][1], 0, 0, 0);
            acc[1][0] = __builtin_amdgcn_mfma_f32_16x16x32_bf16(a1, b0, acc[1][0], 0, 0, 0);
            acc[1][1] = __builtin_amdgcn_mfma_f32_16x16x32_bf16(a1, b1, acc[1][1], 0, 0, 0);
        }
    }
}

// ---------------------------------------------------------------------------
// gemm_zt: zt = Xb @ WtT^T + b_tune   (M=1024, N=128, K=192)
// ---------------------------------------------------------------------------
__global__ __launch_bounds__(256)
void gemm_zt(const unsigned short* __restrict__ Xb, const unsigned short* __restrict__ WtT,
             const float* __restrict__ b_tune, float* __restrict__ zt)
{
    const int cb = blockIdx.x, rb = blockIdx.y;
    __shared__ unsigned short As[64 * LP];
    __shared__ unsigned short Bs[64 * LP];
    const int tid = threadIdx.x, srow = tid >> 2, skc = (tid & 3) << 4;
    const unsigned short* ag = Xb  + (size_t)(rb * 64 + srow) * 192 + skc;
    const unsigned short* bg = WtT + (size_t)(cb * 64 + srow) * 192 + skc;
    const int lane = tid & 63, w = tid >> 6;
    const int wrow = (w >> 1) * 32, wcol = (w & 1) * 32;
    const int fr = lane & 15, fg = lane >> 4, fk = fg << 3;

    f32x4 acc[2][2] = {};
    core_sa(ag, bg, As, Bs, 192, srow, skc, wrow, wcol, fr, fk, acc);

    #pragma unroll
    for (int m = 0; m < 2; ++m) {
        const int gm = rb * 64 + wrow + m * 16 + fg * 4;
        #pragma unroll
        for (int n = 0; n < 2; ++n) {
            const int gj = cb * 64 + wcol + n * 16 + fr;
            const float bb = b_tune[gj];
            #pragma unroll
            for (int r = 0; r < 4; ++r)
                zt[(size_t)(gm + r) * HDIM + gj] = acc[m][n][r] + bb;
        }
    }
}

// ---------------------------------------------------------------------------
// post element
// ---------------------------------------------------------------------------
__device__ __forceinline__ float post_elem(float y1, float y2, float y3, float s,
                                           float g, float u, float dA)
{
    const float bl = -0.1f * y1 + 0.01f * y2;
    const float cq = 0.005f * y3;
    float integ = 0.f;
    #pragma unroll
    for (int k = 0; k < 8; ++k) {
        const float t = c_t[k];
        integ += c_w[k] * (g + t * bl + t * t * cq) * expf(dA * t);
    }
    return u - 0.1f * s + integ;
}

// ---------------------------------------------------------------------------
// gemm_bz: fused row-wise pre-chain + Bz MFMA GEMM.
// grid (2 col-tiles, 32 row-tiles), 128 threads. Tile: 32 rows x 64 cols.
// Phase A: x (stage1: zt; stage2: zt + gelu(post1) with out0 write),
//          rmsnorm -> xn, delta, U (cb==0), xn -> LDS bf16.
// Phase B: Bz = xn @ W_B^T + b_B ; V = Bz*delta -> VU fp32 + VUt bf16^T.
// ---------------------------------------------------------------------------
__global__ __launch_bounds__(128)
void gemm_bz(const float* __restrict__ zt,
             const float* __restrict__ Part, const float* __restrict__ Gf,
             const float* __restrict__ Y1f, const float* __restrict__ Sf,
             const float* __restrict__ dlt_prev, const float* __restrict__ A_prev,
             const float* __restrict__ rms_scale, const unsigned short* __restrict__ WBT,
             const float* __restrict__ b_B, const float* __restrict__ W_dt,
             const float* __restrict__ b_dt, const float* __restrict__ A_log,
             const float* __restrict__ m_vec, const int* __restrict__ act,
             float* __restrict__ VU, unsigned short* __restrict__ VUt,
             float* __restrict__ dlt_out, float* __restrict__ out0)
{
    const int cb = blockIdx.x, rb = blockIdx.y;
    __shared__ unsigned short As[32 * LPA];
    __shared__ float sred[32][4];
    __shared__ float sdlt[32];

    const int tid = threadIdx.x;
    const int lr = tid >> 2, q = tid & 3;
    const int r = rb * 32 + lr;
    const int c0 = q * 32;

    // ---- Phase A ----
    float x[32];
    if (!out0) {
        #pragma unroll
        for (int v4 = 0; v4 < 8; ++v4) {
            float4 v = *(const float4*)(zt + (size_t)r * HDIM + c0 + v4 * 4);
            x[v4 * 4 + 0] = v.x; x[v4 * 4 + 1] = v.y;
            x[v4 * 4 + 2] = v.z; x[v4 * 4 + 3] = v.w;
        }
    } else {
        const float dAl = dlt_prev[r];
        #pragma unroll
        for (int v4 = 0; v4 < 8; ++v4) {
            const int c = c0 + v4 * 4;
            float4 p0 = *(const float4*)(Part + (size_t)r * 256 + c);
            float4 p1 = *(const float4*)(Part + 262144 + (size_t)r * 256 + c);
            float4 p2 = *(const float4*)(Part + (size_t)r * 256 + 128 + c);
            float4 p3 = *(const float4*)(Part + 262144 + (size_t)r * 256 + 128 + c);
            float4 y1 = *(const float4*)(Y1f + (size_t)r * HDIM + c);
            float4 sf = *(const float4*)(Sf + (size_t)r * HDIM + c);
            float4 gg = *(const float4*)(Gf + (size_t)r * HDIM + c);
            float4 uu = *(const float4*)(VU + (size_t)r * 256 + 128 + c);
            float4 aa = *(const float4*)(A_prev + c);
            float4 zz = *(const float4*)(zt + (size_t)r * HDIM + c);
            float4 o4;
            #pragma unroll
            for (int e = 0; e < 4; ++e) {
                const float y2 = ((const float*)&p0)[e] + ((const float*)&p1)[e];
                const float y3 = ((const float*)&p2)[e] + ((const float*)&p3)[e];
                const float dA = -dAl * expf(((const float*)&aa)[e]);
                const float o1 = post_elem(((const float*)&y1)[e], y2, y3,
                                           ((const float*)&sf)[e], ((const float*)&gg)[e],
                                           ((const float*)&uu)[e], dA);
                ((float*)&o4)[e] = o1;
                const float g3 = o1 * o1 * o1;
                const float gel = 0.5f * o1 * (1.0f + tanhf(0.7978845608028654f * (o1 + 0.044715f * g3)));
                x[v4 * 4 + e] = ((const float*)&zz)[e] + gel;
            }
            if (cb == 0) *(float4*)(out0 + (size_t)r * HDIM + c) = o4;
        }
    }

    float ss = 0.f;
    #pragma unroll
    for (int cc = 0; cc < 32; ++cc) ss += x[cc] * x[cc];
    sred[lr][q] = ss;
    __syncthreads();
    const float tot = sred[lr][0] + sred[lr][1] + sred[lr][2] + sred[lr][3];
    const float rms = sqrtf(tot) * 0.08838834764831845f;     // /sqrt(128)
    const float inv = 1.f / (rms + 1e-8f);

    float dp = 0.f;
    #pragma unroll
    for (int cc = 0; cc < 32; ++cc) {
        const int c = c0 + cc;
        const float xn = rms_scale[c] * x[cc] * inv;
        x[cc] = xn;
        dp += xn * W_dt[c];
    }
    __syncthreads();
    sred[lr][q] = dp;
    __syncthreads();
    const float dd = sred[lr][0] + sred[lr][1] + sred[lr][2] + sred[lr][3] + b_dt[0];
    const float delta = dd > 0.f ? dd + log1pf(expf(-dd)) : log1pf(expf(dd));
    if (q == 0) {
        sdlt[lr] = delta;
        if (cb == 0) dlt_out[r] = delta;
    }

    #pragma unroll
    for (int v4 = 0; v4 < 8; ++v4) {
        ushort4 o;
        o.x = f2bf(x[v4 * 4 + 0]); o.y = f2bf(x[v4 * 4 + 1]);
        o.z = f2bf(x[v4 * 4 + 2]); o.w = f2bf(x[v4 * 4 + 3]);
        *(ushort4*)&As[lr * LPA + c0 + v4 * 4] = o;
    }

    if (cb == 0) {                       // U = m * exp(-delta*exp(A_log))
        const int aid = act[r];
        #pragma unroll
        for (int v4 = 0; v4 < 8; ++v4) {
            const int c = c0 + v4 * 4;
            float4 mv = *(const float4*)(m_vec + (size_t)aid * HDIM + c);
            float4 av = *(const float4*)(A_log + c);
            float4 u;
            u.x = mv.x * expf(-delta * expf(av.x));
            u.y = mv.y * expf(-delta * expf(av.y));
            u.z = mv.z * expf(-delta * expf(av.z));
            u.w = mv.w * expf(-delta * expf(av.w));
            *(float4*)(VU + (size_t)r * 256 + 128 + c) = u;
            VUt[(size_t)(128 + c + 0) * 1024 + r] = f2bf(u.x);
            VUt[(size_t)(128 + c + 1) * 1024 + r] = f2bf(u.y);
            VUt[(size_t)(128 + c + 2) * 1024 + r] = f2bf(u.z);
            VUt[(size_t)(128 + c + 3) * 1024 + r] = f2bf(u.w);
        }
    }
    __syncthreads();

    // ---- Phase B: MFMA (32 rows x 64 cols, K=128), B direct from global ----
    const int lane = tid & 63, w = tid >> 6;
    const int wcol = w * 32;
    const int fr = lane & 15, fg = lane >> 4, fk = fg << 3;
    const unsigned short* bbase = WBT + (size_t)cb * 64 * HDIM;

    f32x4 acc[2][2] = {};
    #pragma unroll
    for (int ks = 0; ks < 4; ++ks) {
        const int ko = ks * 32 + fk;
        bf16x8 a0 = *(const bf16x8*)&As[(fr) * LPA + ko];
        bf16x8 a1 = *(const bf16x8*)&As[(16 + fr) * LPA + ko];
        bf16x8 b0 = *(const bf16x8*)(bbase + (size_t)(wcol + fr) * HDIM + ko);
        bf16x8 b1 = *(const bf16x8*)(bbase + (size_t)(wcol + 16 + fr) * HDIM + ko);
        acc[0][0] = __builtin_amdgcn_mfma_f32_16x16x32_bf16(a0, b0, acc[0][0], 0, 0, 0);
        acc[0][1] = __builtin_amdgcn_mfma_f32_16x16x32_bf16(a0, b1, acc[0][1], 0, 0, 0);
        acc[1][0] = __builtin_amdgcn_mfma_f32_16x16x32_bf16(a1, b0, acc[1][0], 0, 0, 0);
        acc[1][1] = __builtin_amdgcn_mfma_f32_16x16x32_bf16(a1, b1, acc[1][1], 0, 0, 0);
    }

    #pragma unroll
    for (int m = 0; m < 2; ++m) {
        const int lrow = m * 16 + fg * 4;
        #pragma unroll
        for (int n = 0; n < 2; ++n) {
            const int col = cb * 64 + wcol + n * 16 + fr;
            const float bb = b_B[col];
            float vv[4];
            #pragma unroll
            for (int rr = 0; rr < 4; ++rr) {
                vv[rr] = (acc[m][n][rr] + bb) * sdlt[lrow + rr];
                VU[(size_t)(rb * 32 + lrow + rr) * 256 + col] = vv[rr];
            }
            ushort4 tv;
            tv.x = f2bf(vv[0]); tv.y = f2bf(vv[1]); tv.z = f2bf(vv[2]); tv.w = f2bf(vv[3]);
            *(ushort4*)&VUt[(size_t)col * 1024 + rb * 32 + lrow] = tv;
        }
    }
}

// ---------------------------------------------------------------------------
// GA: slots 0,1 -> G = V - 0.1 LV ; slots 2,3 -> T = U - 0.1 LU - 0.05 dLU
// ---------------------------------------------------------------------------
__global__ __launch_bounds__(256)
void gemm_ga(const unsigned short* __restrict__ Lb, const unsigned short* __restrict__ dLb,
             const unsigned short* __restrict__ VUt, const float* __restrict__ VU,
             unsigned short* __restrict__ GTt, float* __restrict__ Gf)
{
    const int slot = blockIdx.x, rb = blockIdx.y;
    const bool typeT = slot >= 2;
    const int cb = typeT ? slot - 2 : slot;
    const int bn0 = (typeT ? 128 : 0) + cb * 64;

    __shared__ unsigned short AsL[64 * LP];
    __shared__ unsigned short AsD[64 * LP];
    __shared__ unsigned short Bs[64 * LP];

    const int tid = threadIdx.x;
    const int srow = tid >> 2, skc = (tid & 3) << 4;

    const unsigned short* aL = Lb  + (size_t)(rb * 64 + srow) * 1024 + skc;
    const unsigned short* aD = dLb + (size_t)(rb * 64 + srow) * 1024 + skc;
    const unsigned short* bg = VUt + (size_t)(bn0 + srow) * 1024 + skc;

    const int lane = tid & 63, w = tid >> 6;
    const int wrow = (w >> 1) * 32, wcol = (w & 1) * 32;
    const int fr = lane & 15, fg = lane >> 4, fk = fg << 3;

    f32x4 acc[2][2] = {};
    f32x4 acc2[2][2] = {};

    bf16x8 pa0 = *(const bf16x8*)aL, pa1 = *(const bf16x8*)(aL + 8);
    bf16x8 pb0 = *(const bf16x8*)bg, pb1 = *(const bf16x8*)(bg + 8);
    bf16x8 pd0 = {}, pd1 = {};
    if (typeT) { pd0 = *(const bf16x8*)aD; pd1 = *(const bf16x8*)(aD + 8); }

    for (int k0 = 0; k0 < 1024; k0 += 64) {
        __syncthreads();
        *(bf16x8*)&AsL[srow * LP + skc] = pa0; *(bf16x8*)&AsL[srow * LP + skc + 8] = pa1;
        *(bf16x8*)&Bs[srow * LP + skc]  = pb0; *(bf16x8*)&Bs[srow * LP + skc + 8]  = pb1;
        if (typeT) { *(bf16x8*)&AsD[srow * LP + skc] = pd0; *(bf16x8*)&AsD[srow * LP + skc + 8] = pd1; }
        __syncthreads();
        if (k0 + 64 < 1024) {
            pa0 = *(const bf16x8*)(aL + k0 + 64); pa1 = *(const bf16x8*)(aL + k0 + 72);
            pb0 = *(const bf16x8*)(bg + k0 + 64); pb1 = *(const bf16x8*)(bg + k0 + 72);
            if (typeT) { pd0 = *(const bf16x8*)(aD + k0 + 64); pd1 = *(const bf16x8*)(aD + k0 + 72); }
        }
        #pragma unroll
        for (int h = 0; h < 2; ++h) {
            const int ko = h * 32 + fk;
            bf16x8 a0 = *(const bf16x8*)&AsL[(wrow + fr) * LP + ko];
            bf16x8 a1 = *(const bf16x8*)&AsL[(wrow + 16 + fr) * LP + ko];
            bf16x8 b0 = *(const bf16x8*)&Bs[(wcol + fr) * LP + ko];
            bf16x8 b1 = *(const bf16x8*)&Bs[(wcol + 16 + fr) * LP + ko];
            acc[0][0] = __builtin_amdgcn_mfma_f32_16x16x32_bf16(a0, b0, acc[0][0], 0, 0, 0);
            acc[0][1] = __builtin_amdgcn_mfma_f32_16x16x32_bf16(a0, b1, acc[0][1], 0, 0, 0);
            acc[1][0] = __builtin_amdgcn_mfma_f32_16x16x32_bf16(a1, b0, acc[1][0], 0, 0, 0);
            acc[1][1] = __builtin_amdgcn_mfma_f32_16x16x32_bf16(a1, b1, acc[1][1], 0, 0, 0);
            if (typeT) {
                bf16x8 d0 = *(const bf16x8*)&AsD[(wrow + fr) * LP + ko];
                bf16x8 d1 = *(const bf16x8*)&AsD[(wrow + 16 + fr) * LP + ko];
                acc2[0][0] = __builtin_amdgcn_mfma_f32_16x16x32_bf16(d0, b0, acc2[0][0], 0, 0, 0);
                acc2[0][1] = __builtin_amdgcn_mfma_f32_16x16x32_bf16(d0, b1, acc2[0][1], 0, 0, 0);
                acc2[1][0] = __builtin_amdgcn_mfma_f32_16x16x32_bf16(d1, b0, acc2[1][0], 0, 0, 0);
                acc2[1][1] = __builtin_amdgcn_mfma_f32_16x16x32_bf16(d1, b1, acc2[1][1], 0, 0, 0);
            }
        }
    }

    #pragma unroll
    for (int m = 0; m < 2; ++m) {
        const int gm = rb * 64 + wrow + m * 16 + fg * 4;
        #pragma unroll
        for (int n = 0; n < 2; ++n) {
            const int gj = cb * 64 + wcol + n * 16 + fr;   // 0..127
            float gv[4];
            #pragma unroll
            for (int r = 0; r < 4; ++r) {
                if (!typeT)
                    gv[r] = VU[(size_t)(gm + r) * 256 + gj] - 0.1f * acc[m][n][r];
                else
                    gv[r] = VU[(size_t)(gm + r) * 256 + 128 + gj]
                          - 0.1f * acc[m][n][r] - 0.05f * acc2[m][n][r];
            }
            ushort4 tv; tv.x = f2bf(gv[0]); tv.y = f2bf(gv[1]); tv.z = f2bf(gv[2]); tv.w = f2bf(gv[3]);
            *(ushort4*)&GTt[(size_t)((typeT ? 128 : 0) + gj) * 1024 + gm] = tv;
            if (!typeT) {
                #pragma unroll
                for (int r = 0; r < 4; ++r) Gf[(size_t)(gm + r) * 128 + gj] = gv[r];
            }
        }
    }
}

// ---------------------------------------------------------------------------
// GB: slots 0,1: H = L@G ; slots 2,3: Y1 = dL@G (+fp32) ; slots 4,5: S = dL@T
// ---------------------------------------------------------------------------
__global__ __launch_bounds__(256)
void gemm_gb(const unsigned short* __restrict__ Lb, const unsigned short* __restrict__ dLb,
             const unsigned short* __restrict__ GTt,
             unsigned short* __restrict__ HY1t, float* __restrict__ Y1f,
             float* __restrict__ Sf)
{
    const int slot = blockIdx.x, rb = blockIdx.y;
    const unsigned short* A = (slot < 2) ? Lb : dLb;
    const int jbase = ((slot < 2) ? slot : (slot < 4) ? slot - 2 : slot - 4) * 64;
    const int bn0 = (slot < 4) ? jbase : 128 + jbase;

    __shared__ unsigned short As[64 * LP];
    __shared__ unsigned short Bs[64 * LP];

    const int tid = threadIdx.x;
    const int srow = tid >> 2, skc = (tid & 3) << 4;
    const unsigned short* ag = A   + (size_t)(rb * 64 + srow) * 1024 + skc;
    const unsigned short* bg = GTt + (size_t)(bn0 + srow) * 1024 + skc;

    const int lane = tid & 63, w = tid >> 6;
    const int wrow = (w >> 1) * 32, wcol = (w & 1) * 32;
    const int fr = lane & 15, fg = lane >> 4, fk = fg << 3;

    f32x4 acc[2][2] = {};
    core_sa(ag, bg, As, Bs, 1024, srow, skc, wrow, wcol, fr, fk, acc);

    #pragma unroll
    for (int m = 0; m < 2; ++m) {
        const int gm = rb * 64 + wrow + m * 16 + fg * 4;
        #pragma unroll
        for (int n = 0; n < 2; ++n) {
            const int gj = jbase + wcol + n * 16 + fr;
            if (slot < 4) {
                ushort4 tv;
                tv.x = f2bf(acc[m][n][0]); tv.y = f2bf(acc[m][n][1]);
                tv.z = f2bf(acc[m][n][2]); tv.w = f2bf(acc[m][n][3]);
                *(ushort4*)&HY1t[(size_t)((slot < 2 ? 0 : 128) + gj) * 1024 + gm] = tv;
                if (slot >= 2) {
                    #pragma unroll
                    for (int r = 0; r < 4; ++r) Y1f[(size_t)(gm + r) * 128 + gj] = acc[m][n][r];
                }
            } else {
                #pragma unroll
                for (int r = 0; r < 4; ++r) Sf[(size_t)(gm + r) * 128 + gj] = acc[m][n][r];
            }
        }
    }
}

// ---------------------------------------------------------------------------
// GC: dL @ [H|Y1]  (N=256), split-K S=2 -> Part fp32 partials [s][1024][256]
// ---------------------------------------------------------------------------
__global__ __launch_bounds__(256)
void gemm_gc(const unsigned short* __restrict__ dLb, const unsigned short* __restrict__ HY1t,
             float* __restrict__ Part)
{
    const int cb = blockIdx.x, rb = blockIdx.y, sz = blockIdx.z;
    const int kbase = sz * 512;

    __shared__ unsigned short As[64 * LP];
    __shared__ unsigned short Bs[64 * LP];

    const int tid = threadIdx.x;
    const int srow = tid >> 2, skc = (tid & 3) << 4;
    const unsigned short* ag = dLb  + (size_t)(rb * 64 + srow) * 1024 + kbase + skc;
    const unsigned short* bg = HY1t + (size_t)(cb * 64 + srow) * 1024 + kbase + skc;

    const int lane = tid & 63, w = tid >> 6;
    const int wrow = (w >> 1) * 32, wcol = (w & 1) * 32;
    const int fr = lane & 15, fg = lane >> 4, fk = fg << 3;

    f32x4 acc[2][2] = {};
    core_sa(ag, bg, As, Bs, 512, srow, skc, wrow, wcol, fr, fk, acc);

    float* Cb = Part + (size_t)sz * 262144;
    #pragma unroll
    for (int m = 0; m < 2; ++m) {
        const int gm = rb * 64 + wrow + m * 16 + fg * 4;
        #pragma unroll
        for (int n = 0; n < 2; ++n) {
            const int gn = cb * 64 + wcol + n * 16 + fr;
            #pragma unroll
            for (int r = 0; r < 4; ++r) Cb[(size_t)(gm + r) * 256 + gn] = acc[m][n][r];
        }
    }
}

// ---------------------------------------------------------------------------
// ew_tail: post(stage2) -> out[1]. grid 32 x 128 thr, 32 elems/thread, float4.
// ---------------------------------------------------------------------------
__global__ __launch_bounds__(128)
void ew_tail(const float* __restrict__ Part, const float* __restrict__ Gf,
             const float* __restrict__ Y1f, const float* __restrict__ Sf,
             const float* __restrict__ VU, const float* __restrict__ dlt,
             const float* __restrict__ A_log, float* __restrict__ out)
{
    const int lr = threadIdx.x >> 2, q = threadIdx.x & 3;
    const int r = blockIdx.x * 32 + lr;
    const int c0 = q * 32;
    const float dAl = dlt[r];
    #pragma unroll
    for (int v4 = 0; v4 < 8; ++v4) {
        const int c = c0 + v4 * 4;
        float4 p0 = *(const float4*)(Part + (size_t)r * 256 + c);
        float4 p1 = *(const float4*)(Part + 262144 + (size_t)r * 256 + c);
        float4 p2 = *(const float4*)(Part + (size_t)r * 256 + 128 + c);
        float4 p3 = *(const float4*)(Part + 262144 + (size_t)r * 256 + 128 + c);
        float4 y1 = *(const float4*)(Y1f + (size_t)r * HDIM + c);
        float4 sf = *(const float4*)(Sf + (size_t)r * HDIM + c);
        float4 gg = *(const float4*)(Gf + (size_t)r * HDIM + c);
        float4 uu = *(const float4*)(VU + (size_t)r * 256 + 128 + c);
        float4 aa = *(const float4*)(A_log + c);
        float4 o4;
        #pragma unroll
        for (int e = 0; e < 4; ++e) {
            const float y2 = ((const float*)&p0)[e] + ((const float*)&p1)[e];
            const float y3 = ((const float*)&p2)[e] + ((const float*)&p3)[e];
            const float dA = -dAl * expf(((const float*)&aa)[e]);
            ((float*)&o4)[e] = post_elem(((const float*)&y1)[e], y2, y3,
                                         ((const float*)&sf)[e], ((const float*)&gg)[e],
                                         ((const float*)&uu)[e], dA);
        }
        *(float4*)(out + (size_t)r * HDIM + c) = o4;
    }
}

// ---------------------------------------------------------------------------
extern "C" void kernel_launch(void* const* d_in, const int* in_sizes, int n_in,
                              void* d_out, int out_size, void* d_ws, size_t ws_size,
                              hipStream_t stream)
{
    const float* L      = (const float*)d_in[0];
    const float* dL     = (const float*)d_in[1];
    const float* x_sub  = (const float*)d_in[2];
    const float* m1     = (const float*)d_in[3];
    const float* m2     = (const float*)d_in[4];
    const float* names  = (const float*)d_in[5];
    const float* rms1   = (const float*)d_in[6];
    const float* rms2   = (const float*)d_in[7];
    const float* W_tune = (const float*)d_in[8];
    const float* b_tune = (const float*)d_in[9];
    const float* W_B1   = (const float*)d_in[10];
    const float* b_B1   = (const float*)d_in[11];
    const float* W_B2   = (const float*)d_in[12];
    const float* b_B2   = (const float*)d_in[13];
    const float* W_dt   = (const float*)d_in[14];
    const float* b_dt   = (const float*)d_in[15];
    const float* A1     = (const float*)d_in[16];
    const float* A2     = (const float*)d_in[17];
    const int*   src    = (const int*)d_in[18];
    const int*   dst    = (const int*)d_in[19];
    const int*   act    = (const int*)d_in[20];
    float* out = (float*)d_out;

    // Workspace (~11 MB)
    float* ws   = (float*)d_ws;
    float* zt   = ws;                    // 131072
    float* VU   = zt   + 131072;         // 262144  fp32 [V|U]
    float* Gf   = VU   + 262144;         // 131072
    float* Y1f  = Gf   + 131072;         // 131072
    float* Sf   = Y1f  + 131072;         // 131072
    float* dlt1 = Sf   + 131072;         // 1024
    float* dlt2 = dlt1 + 1024;           // 1024
    float* Part = dlt2 + 1024;           // 524288 (GC partials, S=2)
    unsigned short* Lb    = (unsigned short*)(Part + 524288);   // 1048576
    unsigned short* dLb   = Lb    + 1048576;                    // 1048576
    unsigned short* VUt   = dLb   + 1048576;                    // 262144 [V|U]^T
    unsigned short* GTt   = VUt   + 262144;                     // 262144 [G|T]^T
    unsigned short* HY1t  = GTt   + 262144;                     // 262144 [H|Y1]^T
    unsigned short* Xb    = HY1t  + 262144;                     // 196608 [1024][192]
    unsigned short* WtT   = Xb    + 196608;                     // 24576  [128][192]
    unsigned short* WB1T  = WtT   + 24576;                      // 16384
    unsigned short* WB2T  = WB1T  + 16384;                      // 16384

    conv_all<<<dim3(3040), dim3(256), 0, stream>>>(
        L, dL, x_sub, names, src, dst, W_tune, W_B1, W_B2,
        Lb, dLb, Xb, WtT, WB1T, WB2T);

    gemm_zt<<<dim3(2, 16), dim3(256), 0, stream>>>(Xb, WtT, b_tune, zt);

    // ---- stage 1 ----
    gemm_bz<<<dim3(2, 32), dim3(128), 0, stream>>>(
        zt, nullptr, nullptr, nullptr, nullptr, nullptr, nullptr,
        rms1, WB1T, b_B1, W_dt, b_dt, A1, m1, act,
        VU, VUt, dlt1, nullptr);
    gemm_ga<<<dim3(4, 16), dim3(256), 0, stream>>>(Lb, dLb, VUt, VU, GTt, Gf);
    gemm_gb<<<dim3(6, 16), dim3(256), 0, stream>>>(Lb, dLb, GTt, HY1t, Y1f, Sf);
    gemm_gc<<<dim3(4, 16, 2), dim3(256), 0, stream>>>(dLb, HY1t, Part);

    // ---- stage 2 (fused post1 + gelu + pre2 + Bz2) ----
    gemm_bz<<<dim3(2, 32), dim3(128), 0, stream>>>(
        zt, Part, Gf, Y1f, Sf, dlt1, A1,
        rms2, WB2T, b_B2, W_dt, b_dt, A2, m2, act,
        VU, VUt, dlt2, out);
    gemm_ga<<<dim3(4, 16), dim3(256), 0, stream>>>(Lb, dLb, VUt, VU, GTt, Gf);
    gemm_gb<<<dim3(6, 16), dim3(256), 0, stream>>>(Lb, dLb, GTt, HY1t, Y1f, Sf);
    gemm_gc<<<dim3(4, 16, 2), dim3(256), 0, stream>>>(dLb, HY1t, Part);

    ew_tail<<<dim3(32), dim3(128), 0, stream>>>(
        Part, Gf, Y1f, Sf, VU, dlt2, A2, out + 131072);
}

// Round 9
// 100.383 us; speedup vs baseline: 1.3439x; 1.3439x over previous
//
#include <hip/hip_runtime.h>
#include <math.h>

#define N_A   1024
#define HDIM  128
#define DIN   172
#define E_CNT 256
#define LP    72      // LDS pitch (bf16) for 64-wide GEMM tiles

typedef __attribute__((ext_vector_type(8))) short bf16x8;
typedef __attribute__((ext_vector_type(4))) float f32x4;

__device__ __forceinline__ unsigned short f2bf(float x) {
    unsigned int u = __float_as_uint(x);
    unsigned int r = (u + 0x7fffu + ((u >> 16) & 1u)) >> 16;
    return (unsigned short)r;
}

// Gauss-Legendre nodes/weights mapped to [0,1] (tau=1)
__constant__ float c_t[8] = {
    0.4082826787521751f, 0.2372337950418355f, 0.10166676129318665f, 0.019855071751231843f,
    0.5917173212478249f, 0.7627662049581645f, 0.8983332387068134f, 0.9801449282487682f};
__constant__ float c_w[8] = {
    0.181341891689181f, 0.15685332293894365f, 0.11119051722668725f, 0.05061426814518815f,
    0.181341891689181f, 0.15685332293894365f, 0.11119051722668725f, 0.05061426814518815f};

// ---------------------------------------------------------------------------
// conv_all: all fp32 -> bf16 conversions / transposes
// ---------------------------------------------------------------------------
__global__ __launch_bounds__(256)
void conv_all(const float* __restrict__ L, const float* __restrict__ dL,
              const float* __restrict__ x_sub, const float* __restrict__ names,
              const int* __restrict__ src, const int* __restrict__ dst,
              const float* __restrict__ W_tune, const float* __restrict__ W_B1,
              const float* __restrict__ W_B2,
              unsigned short* __restrict__ Lb, unsigned short* __restrict__ dLb,
              unsigned short* __restrict__ Xb, unsigned short* __restrict__ WtT,
              unsigned short* __restrict__ WB1T, unsigned short* __restrict__ WB2T)
{
    const int b = blockIdx.x, tid = threadIdx.x;
    if (b < 2048) {
        const int t = b * 256 + tid;
        const float* s = (t < 262144) ? L : dL;
        unsigned short* d = (t < 262144) ? Lb : dLb;
        const int q = (t < 262144) ? t : t - 262144;
        float4 v = *(const float4*)(s + (size_t)q * 4);
        ushort4 o;
        o.x = f2bf(v.x); o.y = f2bf(v.y); o.z = f2bf(v.z); o.w = f2bf(v.w);
        *(ushort4*)(d + (size_t)q * 4) = o;
    } else if (b < 2816) {
        const int t = (b - 2048) * 256 + tid;        // 0..196607
        const int i = t / 192, k = t - i * 192;
        float val = 0.f;
        if (k < DIN) val = x_sub[(size_t)i * DIN + k];
        else if (k == DIN) {
            if (i < E_CNT)          val = names[src[i]];
            else if (i < 2 * E_CNT) val = names[dst[i - E_CNT]];
        } else if (k == DIN + 1) {
            if (i < E_CNT)          val = names[dst[i]];
            else if (i < 2 * E_CNT) val = names[src[i - E_CNT]];
        }
        Xb[t] = f2bf(val);
    } else if (b < 2912) {
        const int t = (b - 2816) * 256 + tid;        // 0..24575
        const int j = t / 192, k = t - j * 192;
        WtT[t] = (k < DIN + 2) ? f2bf(W_tune[k * HDIM + j]) : (unsigned short)0;
    } else {
        const int t = (b - 2912) * 256 + tid;        // 0..32767
        const int half = t >> 14, tt = t & 16383;
        const int j = tt >> 7, k = tt & 127;
        (half ? WB2T : WB1T)[tt] = f2bf((half ? W_B2 : W_B1)[k * HDIM + j]);
    }
}

// ---------------------------------------------------------------------------
// single-A 64x64 MFMA core (A,B K-contiguous; K row stride baked into ag/bg)
// ---------------------------------------------------------------------------
__device__ __forceinline__ void core_sa(
    const unsigned short* __restrict__ ag, const unsigned short* __restrict__ bg,
    unsigned short* As, unsigned short* Bs, int klen,
    int srow, int skc, int wrow, int wcol, int fr, int fk, f32x4 (&acc)[2][2])
{
    bf16x8 pa0 = *(const bf16x8*)ag, pa1 = *(const bf16x8*)(ag + 8);
    bf16x8 pb0 = *(const bf16x8*)bg, pb1 = *(const bf16x8*)(bg + 8);
    for (int k0 = 0; k0 < klen; k0 += 64) {
        __syncthreads();
        *(bf16x8*)&As[srow * LP + skc] = pa0; *(bf16x8*)&As[srow * LP + skc + 8] = pa1;
        *(bf16x8*)&Bs[srow * LP + skc] = pb0; *(bf16x8*)&Bs[srow * LP + skc + 8] = pb1;
        __syncthreads();
        if (k0 + 64 < klen) {
            pa0 = *(const bf16x8*)(ag + k0 + 64); pa1 = *(const bf16x8*)(ag + k0 + 72);
            pb0 = *(const bf16x8*)(bg + k0 + 64); pb1 = *(const bf16x8*)(bg + k0 + 72);
        }
        #pragma unroll
        for (int h = 0; h < 2; ++h) {
            const int ko = h * 32 + fk;
            bf16x8 a0 = *(const bf16x8*)&As[(wrow + fr) * LP + ko];
            bf16x8 a1 = *(const bf16x8*)&As[(wrow + 16 + fr) * LP + ko];
            bf16x8 b0 = *(const bf16x8*)&Bs[(wcol + fr) * LP + ko];
            bf16x8 b1 = *(const bf16x8*)&Bs[(wcol + 16 + fr) * LP + ko];
            acc[0][0] = __builtin_amdgcn_mfma_f32_16x16x32_bf16(a0, b0, acc[0][0], 0, 0, 0);
            acc[0][1] = __builtin_amdgcn_mfma_f32_16x16x32_bf16(a0, b1, acc[0][1], 0, 0, 0);
            acc[1][0] = __builtin_amdgcn_mfma_f32_16x16x32_bf16(a1, b0, acc[1][0], 0, 0, 0);
            acc[1][1] = __builtin_amdgcn_mfma_f32_16x16x32_bf16(a1, b1, acc[1][1], 0, 0, 0);
        }
    }
}

// ---------------------------------------------------------------------------
// gemm_zt: zt = Xb @ WtT^T + b_tune   (M=1024, N=128, K=192)
// ---------------------------------------------------------------------------
__global__ __launch_bounds__(256)
void gemm_zt(const unsigned short* __restrict__ Xb, const unsigned short* __restrict__ WtT,
             const float* __restrict__ b_tune, float* __restrict__ zt)
{
    const int cb = blockIdx.x, rb = blockIdx.y;
    __shared__ unsigned short As[64 * LP];
    __shared__ unsigned short Bs[64 * LP];
    const int tid = threadIdx.x, srow = tid >> 2, skc = (tid & 3) << 4;
    const unsigned short* ag = Xb  + (size_t)(rb * 64 + srow) * 192 + skc;
    const unsigned short* bg = WtT + (size_t)(cb * 64 + srow) * 192 + skc;
    const int lane = tid & 63, w = tid >> 6;
    const int wrow = (w >> 1) * 32, wcol = (w & 1) * 32;
    const int fr = lane & 15, fg = lane >> 4, fk = fg << 3;

    f32x4 acc[2][2] = {};
    core_sa(ag, bg, As, Bs, 192, srow, skc, wrow, wcol, fr, fk, acc);

    #pragma unroll
    for (int m = 0; m < 2; ++m) {
        const int gm = rb * 64 + wrow + m * 16 + fg * 4;
        #pragma unroll
        for (int n = 0; n < 2; ++n) {
            const int gj = cb * 64 + wcol + n * 16 + fr;
            const float bb = b_tune[gj];
            #pragma unroll
            for (int r = 0; r < 4; ++r)
                zt[(size_t)(gm + r) * HDIM + gj] = acc[m][n][r] + bb;
        }
    }
}

// ---------------------------------------------------------------------------
// wave-based 128-wide row reduction (2 waves per block)
// ---------------------------------------------------------------------------
__device__ __forceinline__ float rowsum128(float v, float* red2, int j)
{
    #pragma unroll
    for (int o = 32; o > 0; o >>= 1) v += __shfl_xor(v, o, 64);
    if ((j & 63) == 0) red2[j >> 6] = v;
    __syncthreads();
    const float t = red2[0] + red2[1];
    __syncthreads();
    return t;
}

// ---------------------------------------------------------------------------
// rms/delta/U core (one row per block, one col per thread)
// ---------------------------------------------------------------------------
__device__ __forceinline__ void rms_core(
    float x, int i, int j,
    const float* __restrict__ rms_scale, const float* __restrict__ W_dt,
    const float* __restrict__ b_dt, const float* __restrict__ A_log,
    const float* __restrict__ m_vec, const int* __restrict__ act,
    unsigned short* __restrict__ xnb, float* __restrict__ VU,
    unsigned short* __restrict__ VUt, float* __restrict__ dlt, float* red2)
{
    const float ss = rowsum128(x * x, red2, j);
    const float rms = sqrtf(ss) * 0.08838834764831845f;   // /sqrt(128)
    const float xn = rms_scale[j] * x / (rms + 1e-8f);
    const float dsum = rowsum128(xn * W_dt[j], red2, j);
    const float dd = dsum + b_dt[0];
    const float delta = dd > 0.f ? dd + log1pf(expf(-dd)) : log1pf(expf(dd));
    xnb[(size_t)i * HDIM + j] = f2bf(xn);
    const float U = m_vec[(size_t)act[i] * HDIM + j] * expf(-delta * expf(A_log[j]));
    VU[(size_t)i * 256 + 128 + j] = U;
    VUt[(size_t)(128 + j) * 1024 + i] = f2bf(U);
    if (j == 0) dlt[i] = delta;
}

// ---------------------------------------------------------------------------
// rms_dt (stage 1): x = zt row
// ---------------------------------------------------------------------------
__global__ __launch_bounds__(128)
void rms_dt(const float* __restrict__ zt,
            const float* __restrict__ rms_scale, const float* __restrict__ W_dt,
            const float* __restrict__ b_dt, const float* __restrict__ A_log,
            const float* __restrict__ m_vec, const int* __restrict__ act,
            unsigned short* __restrict__ xnb, float* __restrict__ VU,
            unsigned short* __restrict__ VUt, float* __restrict__ dlt)
{
    const int i = blockIdx.x, j = threadIdx.x;
    __shared__ float red2[2];
    rms_core(zt[(size_t)i * HDIM + j], i, j, rms_scale, W_dt, b_dt, A_log,
             m_vec, act, xnb, VU, VUt, dlt, red2);
}

// ---------------------------------------------------------------------------
// post element
// ---------------------------------------------------------------------------
__device__ __forceinline__ float post_elem(float y1, float y2, float y3, float s,
                                           float g, float u, float dA)
{
    const float bl = -0.1f * y1 + 0.01f * y2;
    const float cq = 0.005f * y3;
    float integ = 0.f;
    #pragma unroll
    for (int k = 0; k < 8; ++k) {
        const float t = c_t[k];
        integ += c_w[k] * (g + t * bl + t * t * cq) * expf(dA * t);
    }
    return u - 0.1f * s + integ;
}

// ---------------------------------------------------------------------------
// ew_mid2: out0 = post(stage1); x2 = zt + gelu(out0); then rms/delta/U (stage2)
// one row per block, one col per thread.
// ---------------------------------------------------------------------------
__global__ __launch_bounds__(128)
void ew_mid2(const float* __restrict__ Part, const float* __restrict__ Gf,
             const float* __restrict__ Y1f, const float* __restrict__ Sf,
             const float* __restrict__ zt, const float* __restrict__ dlt1,
             const float* __restrict__ A1,
             const float* __restrict__ rms2, const float* __restrict__ W_dt,
             const float* __restrict__ b_dt, const float* __restrict__ A2,
             const float* __restrict__ m2, const int* __restrict__ act,
             unsigned short* __restrict__ xnb, float* __restrict__ VU,
             unsigned short* __restrict__ VUt, float* __restrict__ dlt2,
             float* __restrict__ out0)
{
    const int i = blockIdx.x, j = threadIdx.x;
    __shared__ float red2[2];
    const int idx = i * HDIM + j;

    const float y2 = Part[(size_t)i * 256 + j] + Part[262144 + (size_t)i * 256 + j];
    const float y3 = Part[(size_t)i * 256 + 128 + j] + Part[262144 + (size_t)i * 256 + 128 + j];
    const float dA = -dlt1[i] * expf(A1[j]);
    const float o1 = post_elem(Y1f[idx], y2, y3, Sf[idx], Gf[idx],
                               VU[(size_t)i * 256 + 128 + j], dA);
    out0[idx] = o1;
    const float g3 = o1 * o1 * o1;
    const float gel = 0.5f * o1 * (1.0f + tanhf(0.7978845608028654f * (o1 + 0.044715f * g3)));
    const float x = zt[idx] + gel;

    rms_core(x, i, j, rms2, W_dt, b_dt, A2, m2, act, xnb, VU, VUt, dlt2, red2);
}

// ---------------------------------------------------------------------------
// gemm_bz2: V = (xnb @ WBT^T + b_B) * dlt   (M=1024, N=128, K=128)
// writes VU fp32 [i][0:128] and VUt bf16 transposed rows 0:128
// ---------------------------------------------------------------------------
__global__ __launch_bounds__(256)
void gemm_bz2(const unsigned short* __restrict__ xnb, const unsigned short* __restrict__ WBT,
              const float* __restrict__ b_B, const float* __restrict__ dlt,
              float* __restrict__ VU, unsigned short* __restrict__ VUt)
{
    const int cb = blockIdx.x, rb = blockIdx.y;
    __shared__ unsigned short As[64 * LP];
    __shared__ unsigned short Bs[64 * LP];
    const int tid = threadIdx.x, srow = tid >> 2, skc = (tid & 3) << 4;
    const unsigned short* ag = xnb + (size_t)(rb * 64 + srow) * HDIM + skc;
    const unsigned short* bg = WBT + (size_t)(cb * 64 + srow) * HDIM + skc;
    const int lane = tid & 63, w = tid >> 6;
    const int wrow = (w >> 1) * 32, wcol = (w & 1) * 32;
    const int fr = lane & 15, fg = lane >> 4, fk = fg << 3;

    f32x4 acc[2][2] = {};
    core_sa(ag, bg, As, Bs, 128, srow, skc, wrow, wcol, fr, fk, acc);

    #pragma unroll
    for (int m = 0; m < 2; ++m) {
        const int gm = rb * 64 + wrow + m * 16 + fg * 4;
        #pragma unroll
        for (int n = 0; n < 2; ++n) {
            const int col = cb * 64 + wcol + n * 16 + fr;
            const float bb = b_B[col];
            float vv[4];
            #pragma unroll
            for (int r = 0; r < 4; ++r) {
                vv[r] = (acc[m][n][r] + bb) * dlt[gm + r];
                VU[(size_t)(gm + r) * 256 + col] = vv[r];
            }
            ushort4 tv;
            tv.x = f2bf(vv[0]); tv.y = f2bf(vv[1]); tv.z = f2bf(vv[2]); tv.w = f2bf(vv[3]);
            *(ushort4*)&VUt[(size_t)col * 1024 + gm] = tv;
        }
    }
}

// ---------------------------------------------------------------------------
// GA: slots 0,1 -> G = V - 0.1 LV ; slots 2,3 -> T = U - 0.1 LU - 0.05 dLU
// ---------------------------------------------------------------------------
__global__ __launch_bounds__(256)
void gemm_ga(const unsigned short* __restrict__ Lb, const unsigned short* __restrict__ dLb,
             const unsigned short* __restrict__ VUt, const float* __restrict__ VU,
             unsigned short* __restrict__ GTt, float* __restrict__ Gf)
{
    const int slot = blockIdx.x, rb = blockIdx.y;
    const bool typeT = slot >= 2;
    const int cb = typeT ? slot - 2 : slot;
    const int bn0 = (typeT ? 128 : 0) + cb * 64;

    __shared__ unsigned short AsL[64 * LP];
    __shared__ unsigned short AsD[64 * LP];
    __shared__ unsigned short Bs[64 * LP];

    const int tid = threadIdx.x;
    const int srow = tid >> 2, skc = (tid & 3) << 4;

    const unsigned short* aL = Lb  + (size_t)(rb * 64 + srow) * 1024 + skc;
    const unsigned short* aD = dLb + (size_t)(rb * 64 + srow) * 1024 + skc;
    const unsigned short* bg = VUt + (size_t)(bn0 + srow) * 1024 + skc;

    const int lane = tid & 63, w = tid >> 6;
    const int wrow = (w >> 1) * 32, wcol = (w & 1) * 32;
    const int fr = lane & 15, fg = lane >> 4, fk = fg << 3;

    f32x4 acc[2][2] = {};
    f32x4 acc2[2][2] = {};

    bf16x8 pa0 = *(const bf16x8*)aL, pa1 = *(const bf16x8*)(aL + 8);
    bf16x8 pb0 = *(const bf16x8*)bg, pb1 = *(const bf16x8*)(bg + 8);
    bf16x8 pd0 = {}, pd1 = {};
    if (typeT) { pd0 = *(const bf16x8*)aD; pd1 = *(const bf16x8*)(aD + 8); }

    for (int k0 = 0; k0 < 1024; k0 += 64) {
        __syncthreads();
        *(bf16x8*)&AsL[srow * LP + skc] = pa0; *(bf16x8*)&AsL[srow * LP + skc + 8] = pa1;
        *(bf16x8*)&Bs[srow * LP + skc]  = pb0; *(bf16x8*)&Bs[srow * LP + skc + 8]  = pb1;
        if (typeT) { *(bf16x8*)&AsD[srow * LP + skc] = pd0; *(bf16x8*)&AsD[srow * LP + skc + 8] = pd1; }
        __syncthreads();
        if (k0 + 64 < 1024) {
            pa0 = *(const bf16x8*)(aL + k0 + 64); pa1 = *(const bf16x8*)(aL + k0 + 72);
            pb0 = *(const bf16x8*)(bg + k0 + 64); pb1 = *(const bf16x8*)(bg + k0 + 72);
            if (typeT) { pd0 = *(const bf16x8*)(aD + k0 + 64); pd1 = *(const bf16x8*)(aD + k0 + 72); }
        }
        #pragma unroll
        for (int h = 0; h < 2; ++h) {
            const int ko = h * 32 + fk;
            bf16x8 a0 = *(const bf16x8*)&AsL[(wrow + fr) * LP + ko];
            bf16x8 a1 = *(const bf16x8*)&AsL[(wrow + 16 + fr) * LP + ko];
            bf16x8 b0 = *(const bf16x8*)&Bs[(wcol + fr) * LP + ko];
            bf16x8 b1 = *(const bf16x8*)&Bs[(wcol + 16 + fr) * LP + ko];
            acc[0][0] = __builtin_amdgcn_mfma_f32_16x16x32_bf16(a0, b0, acc[0][0], 0, 0, 0);
            acc[0][1] = __builtin_amdgcn_mfma_f32_16x16x32_bf16(a0, b1, acc[0][1], 0, 0, 0);
            acc[1][0] = __builtin_amdgcn_mfma_f32_16x16x32_bf16(a1, b0, acc[1][0], 0, 0, 0);
            acc[1][1] = __builtin_amdgcn_mfma_f32_16x16x32_bf16(a1, b1, acc[1][1], 0, 0, 0);
            if (typeT) {
                bf16x8 d0 = *(const bf16x8*)&AsD[(wrow + fr) * LP + ko];
                bf16x8 d1 = *(const bf16x8*)&AsD[(wrow + 16 + fr) * LP + ko];
                acc2[0][0] = __builtin_amdgcn_mfma_f32_16x16x32_bf16(d0, b0, acc2[0][0], 0, 0, 0);
                acc2[0][1] = __builtin_amdgcn_mfma_f32_16x16x32_bf16(d0, b1, acc2[0][1], 0, 0, 0);
                acc2[1][0] = __builtin_amdgcn_mfma_f32_16x16x32_bf16(d1, b0, acc2[1][0], 0, 0, 0);
                acc2[1][1] = __builtin_amdgcn_mfma_f32_16x16x32_bf16(d1, b1, acc2[1][1], 0, 0, 0);
            }
        }
    }

    #pragma unroll
    for (int m = 0; m < 2; ++m) {
        const int gm = rb * 64 + wrow + m * 16 + fg * 4;
        #pragma unroll
        for (int n = 0; n < 2; ++n) {
            const int gj = cb * 64 + wcol + n * 16 + fr;   // 0..127
            float gv[4];
            #pragma unroll
            for (int r = 0; r < 4; ++r) {
                if (!typeT)
                    gv[r] = VU[(size_t)(gm + r) * 256 + gj] - 0.1f * acc[m][n][r];
                else
                    gv[r] = VU[(size_t)(gm + r) * 256 + 128 + gj]
                          - 0.1f * acc[m][n][r] - 0.05f * acc2[m][n][r];
            }
            ushort4 tv; tv.x = f2bf(gv[0]); tv.y = f2bf(gv[1]); tv.z = f2bf(gv[2]); tv.w = f2bf(gv[3]);
            *(ushort4*)&GTt[(size_t)((typeT ? 128 : 0) + gj) * 1024 + gm] = tv;
            if (!typeT) {
                #pragma unroll
                for (int r = 0; r < 4; ++r) Gf[(size_t)(gm + r) * 128 + gj] = gv[r];
            }
        }
    }
}

// ---------------------------------------------------------------------------
// GB: slots 0,1: H = L@G ; slots 2,3: Y1 = dL@G (+fp32) ; slots 4,5: S = dL@T
// ---------------------------------------------------------------------------
__global__ __launch_bounds__(256)
void gemm_gb(const unsigned short* __restrict__ Lb, const unsigned short* __restrict__ dLb,
             const unsigned short* __restrict__ GTt,
             unsigned short* __restrict__ HY1t, float* __restrict__ Y1f,
             float* __restrict__ Sf)
{
    const int slot = blockIdx.x, rb = blockIdx.y;
    const unsigned short* A = (slot < 2) ? Lb : dLb;
    const int jbase = ((slot < 2) ? slot : (slot < 4) ? slot - 2 : slot - 4) * 64;
    const int bn0 = (slot < 4) ? jbase : 128 + jbase;

    __shared__ unsigned short As[64 * LP];
    __shared__ unsigned short Bs[64 * LP];

    const int tid = threadIdx.x;
    const int srow = tid >> 2, skc = (tid & 3) << 4;
    const unsigned short* ag = A   + (size_t)(rb * 64 + srow) * 1024 + skc;
    const unsigned short* bg = GTt + (size_t)(bn0 + srow) * 1024 + skc;

    const int lane = tid & 63, w = tid >> 6;
    const int wrow = (w >> 1) * 32, wcol = (w & 1) * 32;
    const int fr = lane & 15, fg = lane >> 4, fk = fg << 3;

    f32x4 acc[2][2] = {};
    core_sa(ag, bg, As, Bs, 1024, srow, skc, wrow, wcol, fr, fk, acc);

    #pragma unroll
    for (int m = 0; m < 2; ++m) {
        const int gm = rb * 64 + wrow + m * 16 + fg * 4;
        #pragma unroll
        for (int n = 0; n < 2; ++n) {
            const int gj = jbase + wcol + n * 16 + fr;
            if (slot < 4) {
                ushort4 tv;
                tv.x = f2bf(acc[m][n][0]); tv.y = f2bf(acc[m][n][1]);
                tv.z = f2bf(acc[m][n][2]); tv.w = f2bf(acc[m][n][3]);
                *(ushort4*)&HY1t[(size_t)((slot < 2 ? 0 : 128) + gj) * 1024 + gm] = tv;
                if (slot >= 2) {
                    #pragma unroll
                    for (int r = 0; r < 4; ++r) Y1f[(size_t)(gm + r) * 128 + gj] = acc[m][n][r];
                }
            } else {
                #pragma unroll
                for (int r = 0; r < 4; ++r) Sf[(size_t)(gm + r) * 128 + gj] = acc[m][n][r];
            }
        }
    }
}

// ---------------------------------------------------------------------------
// GC: dL @ [H|Y1]  (N=256), split-K S=2 -> Part fp32 partials [s][1024][256]
// ---------------------------------------------------------------------------
__global__ __launch_bounds__(256)
void gemm_gc(const unsigned short* __restrict__ dLb, const unsigned short* __restrict__ HY1t,
             float* __restrict__ Part)
{
    const int cb = blockIdx.x, rb = blockIdx.y, sz = blockIdx.z;
    const int kbase = sz * 512;

    __shared__ unsigned short As[64 * LP];
    __shared__ unsigned short Bs[64 * LP];

    const int tid = threadIdx.x;
    const int srow = tid >> 2, skc = (tid & 3) << 4;
    const unsigned short* ag = dLb  + (size_t)(rb * 64 + srow) * 1024 + kbase + skc;
    const unsigned short* bg = HY1t + (size_t)(cb * 64 + srow) * 1024 + kbase + skc;

    const int lane = tid & 63, w = tid >> 6;
    const int wrow = (w >> 1) * 32, wcol = (w & 1) * 32;
    const int fr = lane & 15, fg = lane >> 4, fk = fg << 3;

    f32x4 acc[2][2] = {};
    core_sa(ag, bg, As, Bs, 512, srow, skc, wrow, wcol, fr, fk, acc);

    float* Cb = Part + (size_t)sz * 262144;
    #pragma unroll
    for (int m = 0; m < 2; ++m) {
        const int gm = rb * 64 + wrow + m * 16 + fg * 4;
        #pragma unroll
        for (int n = 0; n < 2; ++n) {
            const int gn = cb * 64 + wcol + n * 16 + fr;
            #pragma unroll
            for (int r = 0; r < 4; ++r) Cb[(size_t)(gm + r) * 256 + gn] = acc[m][n][r];
        }
    }
}

// ---------------------------------------------------------------------------
// ew_tail: post(stage2) -> out[1], one element per thread
// ---------------------------------------------------------------------------
__global__ __launch_bounds__(256)
void ew_tail(const float* __restrict__ Part, const float* __restrict__ Gf,
             const float* __restrict__ Y1f, const float* __restrict__ Sf,
             const float* __restrict__ VU, const float* __restrict__ dlt,
             const float* __restrict__ A_log, float* __restrict__ out)
{
    const int idx = blockIdx.x * 256 + threadIdx.x;    // 131072
    const int i = idx >> 7, j = idx & 127;
    const float y2 = Part[(size_t)i * 256 + j] + Part[262144 + (size_t)i * 256 + j];
    const float y3 = Part[(size_t)i * 256 + 128 + j] + Part[262144 + (size_t)i * 256 + 128 + j];
    const float dA = -dlt[i] * expf(A_log[j]);
    out[idx] = post_elem(Y1f[idx], y2, y3, Sf[idx], Gf[idx],
                         VU[(size_t)i * 256 + 128 + j], dA);
}

// ---------------------------------------------------------------------------
extern "C" void kernel_launch(void* const* d_in, const int* in_sizes, int n_in,
                              void* d_out, int out_size, void* d_ws, size_t ws_size,
                              hipStream_t stream)
{
    const float* L      = (const float*)d_in[0];
    const float* dL     = (const float*)d_in[1];
    const float* x_sub  = (const float*)d_in[2];
    const float* m1     = (const float*)d_in[3];
    const float* m2     = (const float*)d_in[4];
    const float* names  = (const float*)d_in[5];
    const float* rms1   = (const float*)d_in[6];
    const float* rms2   = (const float*)d_in[7];
    const float* W_tune = (const float*)d_in[8];
    const float* b_tune = (const float*)d_in[9];
    const float* W_B1   = (const float*)d_in[10];
    const float* b_B1   = (const float*)d_in[11];
    const float* W_B2   = (const float*)d_in[12];
    const float* b_B2   = (const float*)d_in[13];
    const float* W_dt   = (const float*)d_in[14];
    const float* b_dt   = (const float*)d_in[15];
    const float* A1     = (const float*)d_in[16];
    const float* A2     = (const float*)d_in[17];
    const int*   src    = (const int*)d_in[18];
    const int*   dst    = (const int*)d_in[19];
    const int*   act    = (const int*)d_in[20];
    float* out = (float*)d_out;

    // Workspace (~12 MB)
    float* ws   = (float*)d_ws;
    float* zt   = ws;                    // 131072
    float* VU   = zt   + 131072;         // 262144  fp32 [V|U]
    float* Gf   = VU   + 262144;         // 131072
    float* Y1f  = Gf   + 131072;         // 131072
    float* Sf   = Y1f  + 131072;         // 131072
    float* dlt1 = Sf   + 131072;         // 1024
    float* dlt2 = dlt1 + 1024;           // 1024
    float* Part = dlt2 + 1024;           // 524288 (GC partials, S=2)
    unsigned short* Lb    = (unsigned short*)(Part + 524288);   // 1048576
    unsigned short* dLb   = Lb    + 1048576;                    // 1048576
    unsigned short* VUt   = dLb   + 1048576;                    // 262144 [V|U]^T
    unsigned short* GTt   = VUt   + 262144;                     // 262144 [G|T]^T
    unsigned short* HY1t  = GTt   + 262144;                     // 262144 [H|Y1]^T
    unsigned short* Xb    = HY1t  + 262144;                     // 196608 [1024][192]
    unsigned short* WtT   = Xb    + 196608;                     // 24576  [128][192]
    unsigned short* WB1T  = WtT   + 24576;                      // 16384
    unsigned short* WB2T  = WB1T  + 16384;                      // 16384
    unsigned short* xnb   = WB2T  + 16384;                      // 131072 [1024][128]

    conv_all<<<dim3(3040), dim3(256), 0, stream>>>(
        L, dL, x_sub, names, src, dst, W_tune, W_B1, W_B2,
        Lb, dLb, Xb, WtT, WB1T, WB2T);

    gemm_zt<<<dim3(2, 16), dim3(256), 0, stream>>>(Xb, WtT, b_tune, zt);

    // ---- stage 1 ----
    rms_dt<<<dim3(1024), dim3(128), 0, stream>>>(
        zt, rms1, W_dt, b_dt, A1, m1, act, xnb, VU, VUt, dlt1);
    gemm_bz2<<<dim3(2, 16), dim3(256), 0, stream>>>(xnb, WB1T, b_B1, dlt1, VU, VUt);
    gemm_ga<<<dim3(4, 16), dim3(256), 0, stream>>>(Lb, dLb, VUt, VU, GTt, Gf);
    gemm_gb<<<dim3(6, 16), dim3(256), 0, stream>>>(Lb, dLb, GTt, HY1t, Y1f, Sf);
    gemm_gc<<<dim3(4, 16, 2), dim3(256), 0, stream>>>(dLb, HY1t, Part);

    // ---- stage 2 ----
    ew_mid2<<<dim3(1024), dim3(128), 0, stream>>>(
        Part, Gf, Y1f, Sf, zt, dlt1, A1,
        rms2, W_dt, b_dt, A2, m2, act,
        xnb, VU, VUt, dlt2, out);
    gemm_bz2<<<dim3(2, 16), dim3(256), 0, stream>>>(xnb, WB2T, b_B2, dlt2, VU, VUt);
    gemm_ga<<<dim3(4, 16), dim3(256), 0, stream>>>(Lb, dLb, VUt, VU, GTt, Gf);
    gemm_gb<<<dim3(6, 16), dim3(256), 0, stream>>>(Lb, dLb, GTt, HY1t, Y1f, Sf);
    gemm_gc<<<dim3(4, 16, 2), dim3(256), 0, stream>>>(dLb, HY1t, Part);

    ew_tail<<<dim3(512), dim3(256), 0, stream>>>(
        Part, Gf, Y1f, Sf, VU, dlt2, A2, out + 131072);
}

// Round 10
// 97.809 us; speedup vs baseline: 1.3793x; 1.0263x over previous
//
#include <hip/hip_runtime.h>
#include <math.h>

#define N_A   1024
#define HDIM  128
#define DIN   172
#define E_CNT 256
#define LP    72      // LDS pitch (bf16) for 64-wide GEMM tiles

typedef __attribute__((ext_vector_type(8))) short bf16x8;
typedef __attribute__((ext_vector_type(4))) float f32x4;

__device__ __forceinline__ unsigned short f2bf(float x) {
    unsigned int u = __float_as_uint(x);
    unsigned int r = (u + 0x7fffu + ((u >> 16) & 1u)) >> 16;
    return (unsigned short)r;
}

// Gauss-Legendre nodes/weights mapped to [0,1] (tau=1)
__constant__ float c_t[8] = {
    0.4082826787521751f, 0.2372337950418355f, 0.10166676129318665f, 0.019855071751231843f,
    0.5917173212478249f, 0.7627662049581645f, 0.8983332387068134f, 0.9801449282487682f};
__constant__ float c_w[8] = {
    0.181341891689181f, 0.15685332293894365f, 0.11119051722668725f, 0.05061426814518815f,
    0.181341891689181f, 0.15685332293894365f, 0.11119051722668725f, 0.05061426814518815f};

// ---------------------------------------------------------------------------
// conv_all: fp32 -> bf16 conversions / transposes
//  [0,2048):     L,dL -> Lb,dLb (row-major)
//  [2048,2816):  x_in -> Xb [1024][192]
//  [2816,2912):  W_tune^T -> WtT [128][192]
//  [2912,3040):  W_B1^T, W_B2^T -> WB1T/WB2T
//  [3040,3552):  L^T, dL^T -> LbT, dLbT (64x64 LDS-tiled transpose)
// ---------------------------------------------------------------------------
__global__ __launch_bounds__(256)
void conv_all(const float* __restrict__ L, const float* __restrict__ dL,
              const float* __restrict__ x_sub, const float* __restrict__ names,
              const int* __restrict__ src, const int* __restrict__ dst,
              const float* __restrict__ W_tune, const float* __restrict__ W_B1,
              const float* __restrict__ W_B2,
              unsigned short* __restrict__ Lb, unsigned short* __restrict__ dLb,
              unsigned short* __restrict__ LbT, unsigned short* __restrict__ dLbT,
              unsigned short* __restrict__ Xb, unsigned short* __restrict__ WtT,
              unsigned short* __restrict__ WB1T, unsigned short* __restrict__ WB2T)
{
    __shared__ unsigned short tl[64][72];
    const int b = blockIdx.x, tid = threadIdx.x;
    if (b < 2048) {
        const int t = b * 256 + tid;
        const float* s = (t < 262144) ? L : dL;
        unsigned short* d = (t < 262144) ? Lb : dLb;
        const int q = (t < 262144) ? t : t - 262144;
        float4 v = *(const float4*)(s + (size_t)q * 4);
        ushort4 o;
        o.x = f2bf(v.x); o.y = f2bf(v.y); o.z = f2bf(v.z); o.w = f2bf(v.w);
        *(ushort4*)(d + (size_t)q * 4) = o;
    } else if (b < 2816) {
        const int t = (b - 2048) * 256 + tid;        // 0..196607
        const int i = t / 192, k = t - i * 192;
        float val = 0.f;
        if (k < DIN) val = x_sub[(size_t)i * DIN + k];
        else if (k == DIN) {
            if (i < E_CNT)          val = names[src[i]];
            else if (i < 2 * E_CNT) val = names[dst[i - E_CNT]];
        } else if (k == DIN + 1) {
            if (i < E_CNT)          val = names[dst[i]];
            else if (i < 2 * E_CNT) val = names[src[i - E_CNT]];
        }
        Xb[t] = f2bf(val);
    } else if (b < 2912) {
        const int t = (b - 2816) * 256 + tid;        // 0..24575
        const int j = t / 192, k = t - j * 192;
        WtT[t] = (k < DIN + 2) ? f2bf(W_tune[k * HDIM + j]) : (unsigned short)0;
    } else if (b < 3040) {
        const int t = (b - 2912) * 256 + tid;        // 0..32767
        const int half = t >> 14, tt = t & 16383;
        const int j = tt >> 7, k = tt & 127;
        (half ? WB2T : WB1T)[tt] = f2bf((half ? W_B2 : W_B1)[k * HDIM + j]);
    } else {
        const int t = b - 3040;                      // 0..511
        const float* s = (t < 256) ? L : dL;
        unsigned short* d = (t < 256) ? LbT : dLbT;
        const int tile = t & 255, tr = tile >> 4, tc = tile & 15;
        const int row = tid >> 2, cg = (tid & 3) << 4;
        #pragma unroll
        for (int e = 0; e < 4; ++e) {
            float4 v = *(const float4*)(s + (size_t)(tr * 64 + row) * 1024 + tc * 64 + cg + e * 4);
            tl[row][cg + e * 4 + 0] = f2bf(v.x);
            tl[row][cg + e * 4 + 1] = f2bf(v.y);
            tl[row][cg + e * 4 + 2] = f2bf(v.z);
            tl[row][cg + e * 4 + 3] = f2bf(v.w);
        }
        __syncthreads();
        unsigned short* drow = d + (size_t)(tc * 64 + row) * 1024 + tr * 64 + cg;
        #pragma unroll
        for (int e = 0; e < 4; ++e) {
            ushort4 o;
            o.x = tl[cg + e * 4 + 0][row];
            o.y = tl[cg + e * 4 + 1][row];
            o.z = tl[cg + e * 4 + 2][row];
            o.w = tl[cg + e * 4 + 3][row];
            *(ushort4*)(drow + e * 4) = o;
        }
    }
}

// ---------------------------------------------------------------------------
// single-A 64x64 MFMA core (A,B K-contiguous; K row stride 1024 unless klen<1024 path)
// ---------------------------------------------------------------------------
__device__ __forceinline__ void core_sa(
    const unsigned short* __restrict__ ag, const unsigned short* __restrict__ bg,
    unsigned short* As, unsigned short* Bs, int klen,
    int srow, int skc, int wrow, int wcol, int fr, int fk, f32x4 (&acc)[2][2])
{
    bf16x8 pa0 = *(const bf16x8*)ag, pa1 = *(const bf16x8*)(ag + 8);
    bf16x8 pb0 = *(const bf16x8*)bg, pb1 = *(const bf16x8*)(bg + 8);
    for (int k0 = 0; k0 < klen; k0 += 64) {
        __syncthreads();
        *(bf16x8*)&As[srow * LP + skc] = pa0; *(bf16x8*)&As[srow * LP + skc + 8] = pa1;
        *(bf16x8*)&Bs[srow * LP + skc] = pb0; *(bf16x8*)&Bs[srow * LP + skc + 8] = pb1;
        __syncthreads();
        if (k0 + 64 < klen) {
            pa0 = *(const bf16x8*)(ag + k0 + 64); pa1 = *(const bf16x8*)(ag + k0 + 72);
            pb0 = *(const bf16x8*)(bg + k0 + 64); pb1 = *(const bf16x8*)(bg + k0 + 72);
        }
        #pragma unroll
        for (int h = 0; h < 2; ++h) {
            const int ko = h * 32 + fk;
            bf16x8 a0 = *(const bf16x8*)&As[(wrow + fr) * LP + ko];
            bf16x8 a1 = *(const bf16x8*)&As[(wrow + 16 + fr) * LP + ko];
            bf16x8 b0 = *(const bf16x8*)&Bs[(wcol + fr) * LP + ko];
            bf16x8 b1 = *(const bf16x8*)&Bs[(wcol + 16 + fr) * LP + ko];
            acc[0][0] = __builtin_amdgcn_mfma_f32_16x16x32_bf16(a0, b0, acc[0][0], 0, 0, 0);
            acc[0][1] = __builtin_amdgcn_mfma_f32_16x16x32_bf16(a0, b1, acc[0][1], 0, 0, 0);
            acc[1][0] = __builtin_amdgcn_mfma_f32_16x16x32_bf16(a1, b0, acc[1][0], 0, 0, 0);
            acc[1][1] = __builtin_amdgcn_mfma_f32_16x16x32_bf16(a1, b1, acc[1][1], 0, 0, 0);
        }
    }
}

// ---------------------------------------------------------------------------
// gemm_p12: P1 = dL@L, P2 = dL@dL, stored row-major bf16 via transpose trick:
//   unit0: A=LbT,  Bt=dLb -> D[i][m] = P1[m][i]; store out[m][i] (ushort4/rows)
//   unit1: A=dLbT, Bt=dLb -> D[i][m] = P2[m][i]
// grid (32, 16): blockIdx.x = unit*16 + cb
// ---------------------------------------------------------------------------
__global__ __launch_bounds__(256)
void gemm_p12(const unsigned short* __restrict__ LbT, const unsigned short* __restrict__ dLbT,
              const unsigned short* __restrict__ dLb,
              unsigned short* __restrict__ P1b, unsigned short* __restrict__ P2b)
{
    const int unit = blockIdx.x >> 4, cb = blockIdx.x & 15, rb = blockIdx.y;
    const unsigned short* A = unit ? dLbT : LbT;
    unsigned short* O = unit ? P2b : P1b;

    __shared__ unsigned short As[64 * LP];
    __shared__ unsigned short Bs[64 * LP];
    const int tid = threadIdx.x, srow = tid >> 2, skc = (tid & 3) << 4;
    const unsigned short* ag = A   + (size_t)(rb * 64 + srow) * 1024 + skc;
    const unsigned short* bg = dLb + (size_t)(cb * 64 + srow) * 1024 + skc;
    const int lane = tid & 63, w = tid >> 6;
    const int wrow = (w >> 1) * 32, wcol = (w & 1) * 32;
    const int fr = lane & 15, fg = lane >> 4, fk = fg << 3;

    f32x4 acc[2][2] = {};
    core_sa(ag, bg, As, Bs, 1024, srow, skc, wrow, wcol, fr, fk, acc);

    #pragma unroll
    for (int m = 0; m < 2; ++m) {
        const int gm = rb * 64 + wrow + m * 16 + fg * 4;     // i index
        #pragma unroll
        for (int n = 0; n < 2; ++n) {
            const int gj = cb * 64 + wcol + n * 16 + fr;     // m index
            ushort4 tv;
            tv.x = f2bf(acc[m][n][0]); tv.y = f2bf(acc[m][n][1]);
            tv.z = f2bf(acc[m][n][2]); tv.w = f2bf(acc[m][n][3]);
            *(ushort4*)&O[(size_t)gj * 1024 + gm] = tv;      // O[m][i] row-major
        }
    }
}

// ---------------------------------------------------------------------------
// gemm_zt: zt = Xb @ WtT^T + b_tune   (M=1024, N=128, K=192)
// ---------------------------------------------------------------------------
__global__ __launch_bounds__(256)
void gemm_zt(const unsigned short* __restrict__ Xb, const unsigned short* __restrict__ WtT,
             const float* __restrict__ b_tune, float* __restrict__ zt)
{
    const int cb = blockIdx.x, rb = blockIdx.y;
    __shared__ unsigned short As[64 * LP];
    __shared__ unsigned short Bs[64 * LP];
    const int tid = threadIdx.x, srow = tid >> 2, skc = (tid & 3) << 4;
    const unsigned short* ag = Xb  + (size_t)(rb * 64 + srow) * 192 + skc;
    const unsigned short* bg = WtT + (size_t)(cb * 64 + srow) * 192 + skc;
    const int lane = tid & 63, w = tid >> 6;
    const int wrow = (w >> 1) * 32, wcol = (w & 1) * 32;
    const int fr = lane & 15, fg = lane >> 4, fk = fg << 3;

    f32x4 acc[2][2] = {};
    core_sa(ag, bg, As, Bs, 192, srow, skc, wrow, wcol, fr, fk, acc);

    #pragma unroll
    for (int m = 0; m < 2; ++m) {
        const int gm = rb * 64 + wrow + m * 16 + fg * 4;
        #pragma unroll
        for (int n = 0; n < 2; ++n) {
            const int gj = cb * 64 + wcol + n * 16 + fr;
            const float bb = b_tune[gj];
            #pragma unroll
            for (int r = 0; r < 4; ++r)
                zt[(size_t)(gm + r) * HDIM + gj] = acc[m][n][r] + bb;
        }
    }
}

// ---------------------------------------------------------------------------
// wave-based 128-wide row reduction (2 waves per block)
// ---------------------------------------------------------------------------
__device__ __forceinline__ float rowsum128(float v, float* red2, int j)
{
    #pragma unroll
    for (int o = 32; o > 0; o >>= 1) v += __shfl_xor(v, o, 64);
    if ((j & 63) == 0) red2[j >> 6] = v;
    __syncthreads();
    const float t = red2[0] + red2[1];
    __syncthreads();
    return t;
}

// ---------------------------------------------------------------------------
// rms/delta/U core (one row per block, one col per thread)
// ---------------------------------------------------------------------------
__device__ __forceinline__ void rms_core(
    float x, int i, int j,
    const float* __restrict__ rms_scale, const float* __restrict__ W_dt,
    const float* __restrict__ b_dt, const float* __restrict__ A_log,
    const float* __restrict__ m_vec, const int* __restrict__ act,
    unsigned short* __restrict__ xnb, float* __restrict__ VU,
    unsigned short* __restrict__ VUt, float* __restrict__ dlt, float* red2)
{
    const float ss = rowsum128(x * x, red2, j);
    const float rms = sqrtf(ss) * 0.08838834764831845f;   // /sqrt(128)
    const float xn = rms_scale[j] * x / (rms + 1e-8f);
    const float dsum = rowsum128(xn * W_dt[j], red2, j);
    const float dd = dsum + b_dt[0];
    const float delta = dd > 0.f ? dd + log1pf(expf(-dd)) : log1pf(expf(dd));
    xnb[(size_t)i * HDIM + j] = f2bf(xn);
    const float U = m_vec[(size_t)act[i] * HDIM + j] * expf(-delta * expf(A_log[j]));
    VU[(size_t)i * 256 + 128 + j] = U;
    VUt[(size_t)(128 + j) * 1024 + i] = f2bf(U);
    if (j == 0) dlt[i] = delta;
}

__global__ __launch_bounds__(128)
void rms_dt(const float* __restrict__ zt,
            const float* __restrict__ rms_scale, const float* __restrict__ W_dt,
            const float* __restrict__ b_dt, const float* __restrict__ A_log,
            const float* __restrict__ m_vec, const int* __restrict__ act,
            unsigned short* __restrict__ xnb, float* __restrict__ VU,
            unsigned short* __restrict__ VUt, float* __restrict__ dlt)
{
    const int i = blockIdx.x, j = threadIdx.x;
    __shared__ float red2[2];
    rms_core(zt[(size_t)i * HDIM + j], i, j, rms_scale, W_dt, b_dt, A_log,
             m_vec, act, xnb, VU, VUt, dlt, red2);
}

// ---------------------------------------------------------------------------
// post element
// ---------------------------------------------------------------------------
__device__ __forceinline__ float post_elem(float y1, float y2, float y3, float s,
                                           float g, float u, float dA)
{
    const float bl = -0.1f * y1 + 0.01f * y2;
    const float cq = 0.005f * y3;
    float integ = 0.f;
    #pragma unroll
    for (int k = 0; k < 8; ++k) {
        const float t = c_t[k];
        integ += c_w[k] * (g + t * bl + t * t * cq) * expf(dA * t);
    }
    return u - 0.1f * s + integ;
}

// ---------------------------------------------------------------------------
// ew_mid2: out0 = post(stage1); x2 = zt + gelu(out0); then rms/delta/U (stage2)
// ---------------------------------------------------------------------------
__global__ __launch_bounds__(128)
void ew_mid2(const float* __restrict__ Y1f, const float* __restrict__ Y2f,
             const float* __restrict__ Y3f, const float* __restrict__ Sf,
             const float* __restrict__ Gf,
             const float* __restrict__ zt, const float* __restrict__ dlt1,
             const float* __restrict__ A1,
             const float* __restrict__ rms2, const float* __restrict__ W_dt,
             const float* __restrict__ b_dt, const float* __restrict__ A2,
             const float* __restrict__ m2, const int* __restrict__ act,
             unsigned short* __restrict__ xnb, float* __restrict__ VU,
             unsigned short* __restrict__ VUt, float* __restrict__ dlt2,
             float* __restrict__ out0)
{
    const int i = blockIdx.x, j = threadIdx.x;
    __shared__ float red2[2];
    const int idx = i * HDIM + j;

    const float dA = -dlt1[i] * expf(A1[j]);
    const float o1 = post_elem(Y1f[idx], Y2f[idx], Y3f[idx], Sf[idx], Gf[idx],
                               VU[(size_t)i * 256 + 128 + j], dA);
    out0[idx] = o1;
    const float g3 = o1 * o1 * o1;
    const float gel = 0.5f * o1 * (1.0f + tanhf(0.7978845608028654f * (o1 + 0.044715f * g3)));
    const float x = zt[idx] + gel;

    rms_core(x, i, j, rms2, W_dt, b_dt, A2, m2, act, xnb, VU, VUt, dlt2, red2);
}

// ---------------------------------------------------------------------------
// gemm_bz2: V = (xnb @ WBT^T + b_B) * dlt   (M=1024, N=128, K=128)
// ---------------------------------------------------------------------------
__global__ __launch_bounds__(256)
void gemm_bz2(const unsigned short* __restrict__ xnb, const unsigned short* __restrict__ WBT,
              const float* __restrict__ b_B, const float* __restrict__ dlt,
              float* __restrict__ VU, unsigned short* __restrict__ VUt)
{
    const int cb = blockIdx.x, rb = blockIdx.y;
    __shared__ unsigned short As[64 * LP];
    __shared__ unsigned short Bs[64 * LP];
    const int tid = threadIdx.x, srow = tid >> 2, skc = (tid & 3) << 4;
    const unsigned short* ag = xnb + (size_t)(rb * 64 + srow) * HDIM + skc;
    const unsigned short* bg = WBT + (size_t)(cb * 64 + srow) * HDIM + skc;
    const int lane = tid & 63, w = tid >> 6;
    const int wrow = (w >> 1) * 32, wcol = (w & 1) * 32;
    const int fr = lane & 15, fg = lane >> 4, fk = fg << 3;

    f32x4 acc[2][2] = {};
    core_sa(ag, bg, As, Bs, 128, srow, skc, wrow, wcol, fr, fk, acc);

    #pragma unroll
    for (int m = 0; m < 2; ++m) {
        const int gm = rb * 64 + wrow + m * 16 + fg * 4;
        #pragma unroll
        for (int n = 0; n < 2; ++n) {
            const int col = cb * 64 + wcol + n * 16 + fr;
            const float bb = b_B[col];
            float vv[4];
            #pragma unroll
            for (int r = 0; r < 4; ++r) {
                vv[r] = (acc[m][n][r] + bb) * dlt[gm + r];
                VU[(size_t)(gm + r) * 256 + col] = vv[r];
            }
            ushort4 tv;
            tv.x = f2bf(vv[0]); tv.y = f2bf(vv[1]); tv.z = f2bf(vv[2]); tv.w = f2bf(vv[3]);
            *(ushort4*)&VUt[(size_t)col * 1024 + gm] = tv;
        }
    }
}

// ---------------------------------------------------------------------------
// GA (32-row tiles): slots 0,1 -> G = V - 0.1 LV ; slots 2,3 -> T = U - 0.1 LU - 0.05 dLU
// grid (4, 32). Tile 32 x 64, 4 waves n-split (16 cols each).
// ---------------------------------------------------------------------------
__global__ __launch_bounds__(256)
void gemm_ga(const unsigned short* __restrict__ Lb, const unsigned short* __restrict__ dLb,
             const unsigned short* __restrict__ VUt, const float* __restrict__ VU,
             unsigned short* __restrict__ GTt, float* __restrict__ Gf)
{
    const int slot = blockIdx.x, rb = blockIdx.y;      // rb 0..31
    const bool typeT = slot >= 2;
    const int cb = typeT ? slot - 2 : slot;
    const int bn0 = (typeT ? 128 : 0) + cb * 64;

    __shared__ unsigned short AsL[32 * LP];
    __shared__ unsigned short AsD[32 * LP];
    __shared__ unsigned short Bs[64 * LP];

    const int tid = threadIdx.x;
    const int sar = tid >> 3, sac = (tid & 7) << 3;    // A: 32 rows x 64 k
    const int sbr = tid >> 2, sbc = (tid & 3) << 4;    // B: 64 rows x 64 k

    const unsigned short* aL = Lb  + (size_t)(rb * 32 + sar) * 1024 + sac;
    const unsigned short* aD = dLb + (size_t)(rb * 32 + sar) * 1024 + sac;
    const unsigned short* bg = VUt + (size_t)(bn0 + sbr) * 1024 + sbc;

    const int lane = tid & 63, w = tid >> 6;           // wave -> n offset w*16
    const int fr = lane & 15, fg = lane >> 4, fk = fg << 3;

    f32x4 acc[2] = {};
    f32x4 acc2[2] = {};

    bf16x8 pa = *(const bf16x8*)aL;
    bf16x8 pd = {};
    if (typeT) pd = *(const bf16x8*)aD;
    bf16x8 pb0 = *(const bf16x8*)bg, pb1 = *(const bf16x8*)(bg + 8);

    for (int k0 = 0; k0 < 1024; k0 += 64) {
        __syncthreads();
        *(bf16x8*)&AsL[sar * LP + sac] = pa;
        if (typeT) *(bf16x8*)&AsD[sar * LP + sac] = pd;
        *(bf16x8*)&Bs[sbr * LP + sbc] = pb0; *(bf16x8*)&Bs[sbr * LP + sbc + 8] = pb1;
        __syncthreads();
        if (k0 + 64 < 1024) {
            pa = *(const bf16x8*)(aL + k0 + 64);
            if (typeT) pd = *(const bf16x8*)(aD + k0 + 64);
            pb0 = *(const bf16x8*)(bg + k0 + 64); pb1 = *(const bf16x8*)(bg + k0 + 72);
        }
        #pragma unroll
        for (int h = 0; h < 2; ++h) {
            const int ko = h * 32 + fk;
            bf16x8 a0 = *(const bf16x8*)&AsL[fr * LP + ko];
            bf16x8 a1 = *(const bf16x8*)&AsL[(16 + fr) * LP + ko];
            bf16x8 b0 = *(const bf16x8*)&Bs[(w * 16 + fr) * LP + ko];
            acc[0] = __builtin_amdgcn_mfma_f32_16x16x32_bf16(a0, b0, acc[0], 0, 0, 0);
            acc[1] = __builtin_amdgcn_mfma_f32_16x16x32_bf16(a1, b0, acc[1], 0, 0, 0);
            if (typeT) {
                bf16x8 d0 = *(const bf16x8*)&AsD[fr * LP + ko];
                bf16x8 d1 = *(const bf16x8*)&AsD[(16 + fr) * LP + ko];
                acc2[0] = __builtin_amdgcn_mfma_f32_16x16x32_bf16(d0, b0, acc2[0], 0, 0, 0);
                acc2[1] = __builtin_amdgcn_mfma_f32_16x16x32_bf16(d1, b0, acc2[1], 0, 0, 0);
            }
        }
    }

    #pragma unroll
    for (int m = 0; m < 2; ++m) {
        const int gm = rb * 32 + m * 16 + fg * 4;
        const int gj = cb * 64 + w * 16 + fr;          // 0..127
        float gv[4];
        #pragma unroll
        for (int r = 0; r < 4; ++r) {
            if (!typeT)
                gv[r] = VU[(size_t)(gm + r) * 256 + gj] - 0.1f * acc[m][r];
            else
                gv[r] = VU[(size_t)(gm + r) * 256 + 128 + gj]
                      - 0.1f * acc[m][r] - 0.05f * acc2[m][r];
        }
        ushort4 tv; tv.x = f2bf(gv[0]); tv.y = f2bf(gv[1]); tv.z = f2bf(gv[2]); tv.w = f2bf(gv[3]);
        *(ushort4*)&GTt[(size_t)((typeT ? 128 : 0) + gj) * 1024 + gm] = tv;
        if (!typeT) {
            #pragma unroll
            for (int r = 0; r < 4; ++r) Gf[(size_t)(gm + r) * 128 + gj] = gv[r];
        }
    }
}

// ---------------------------------------------------------------------------
// GB': 4 units x (2 cb) x 16 rb = 128 blocks.
//   unit0: Y1 = dL@G ; unit1: Y2 = P1@G ; unit2: Y3 = P2@G ; unit3: S = dL@T
// All outputs fp32 [1024][128].
// ---------------------------------------------------------------------------
__global__ __launch_bounds__(256)
void gemm_gb(const unsigned short* __restrict__ dLb, const unsigned short* __restrict__ P1b,
             const unsigned short* __restrict__ P2b, const unsigned short* __restrict__ GTt,
             float* __restrict__ Y1f, float* __restrict__ Y2f,
             float* __restrict__ Y3f, float* __restrict__ Sf)
{
    const int unit = blockIdx.x >> 1, cb = blockIdx.x & 1, rb = blockIdx.y;
    const unsigned short* A = (unit == 1) ? P1b : (unit == 2) ? P2b : dLb;
    const int bn0 = (unit == 3 ? 128 : 0) + cb * 64;
    float* O = unit == 0 ? Y1f : unit == 1 ? Y2f : unit == 2 ? Y3f : Sf;

    __shared__ unsigned short As[64 * LP];
    __shared__ unsigned short Bs[64 * LP];

    const int tid = threadIdx.x;
    const int srow = tid >> 2, skc = (tid & 3) << 4;
    const unsigned short* ag = A   + (size_t)(rb * 64 + srow) * 1024 + skc;
    const unsigned short* bg = GTt + (size_t)(bn0 + srow) * 1024 + skc;

    const int lane = tid & 63, w = tid >> 6;
    const int wrow = (w >> 1) * 32, wcol = (w & 1) * 32;
    const int fr = lane & 15, fg = lane >> 4, fk = fg << 3;

    f32x4 acc[2][2] = {};
    core_sa(ag, bg, As, Bs, 1024, srow, skc, wrow, wcol, fr, fk, acc);

    #pragma unroll
    for (int m = 0; m < 2; ++m) {
        const int gm = rb * 64 + wrow + m * 16 + fg * 4;
        #pragma unroll
        for (int n = 0; n < 2; ++n) {
            const int gj = cb * 64 + wcol + n * 16 + fr;
            #pragma unroll
            for (int r = 0; r < 4; ++r) O[(size_t)(gm + r) * 128 + gj] = acc[m][n][r];
        }
    }
}

// ---------------------------------------------------------------------------
// ew_tail: post(stage2) -> out[1]
// ---------------------------------------------------------------------------
__global__ __launch_bounds__(256)
void ew_tail(const float* __restrict__ Y1f, const float* __restrict__ Y2f,
             const float* __restrict__ Y3f, const float* __restrict__ Sf,
             const float* __restrict__ Gf,
             const float* __restrict__ VU, const float* __restrict__ dlt,
             const float* __restrict__ A_log, float* __restrict__ out)
{
    const int idx = blockIdx.x * 256 + threadIdx.x;    // 131072
    const int i = idx >> 7, j = idx & 127;
    const float dA = -dlt[i] * expf(A_log[j]);
    out[idx] = post_elem(Y1f[idx], Y2f[idx], Y3f[idx], Sf[idx], Gf[idx],
                         VU[(size_t)i * 256 + 128 + j], dA);
}

// ---------------------------------------------------------------------------
extern "C" void kernel_launch(void* const* d_in, const int* in_sizes, int n_in,
                              void* d_out, int out_size, void* d_ws, size_t ws_size,
                              hipStream_t stream)
{
    const float* L      = (const float*)d_in[0];
    const float* dL     = (const float*)d_in[1];
    const float* x_sub  = (const float*)d_in[2];
    const float* m1     = (const float*)d_in[3];
    const float* m2     = (const float*)d_in[4];
    const float* names  = (const float*)d_in[5];
    const float* rms1   = (const float*)d_in[6];
    const float* rms2   = (const float*)d_in[7];
    const float* W_tune = (const float*)d_in[8];
    const float* b_tune = (const float*)d_in[9];
    const float* W_B1   = (const float*)d_in[10];
    const float* b_B1   = (const float*)d_in[11];
    const float* W_B2   = (const float*)d_in[12];
    const float* b_B2   = (const float*)d_in[13];
    const float* W_dt   = (const float*)d_in[14];
    const float* b_dt   = (const float*)d_in[15];
    const float* A1     = (const float*)d_in[16];
    const float* A2     = (const float*)d_in[17];
    const int*   src    = (const int*)d_in[18];
    const int*   dst    = (const int*)d_in[19];
    const int*   act    = (const int*)d_in[20];
    float* out = (float*)d_out;

    // Workspace (~19 MB)
    float* ws   = (float*)d_ws;
    float* zt   = ws;                    // 131072
    float* VU   = zt   + 131072;         // 262144  fp32 [V|U]
    float* Gf   = VU   + 262144;         // 131072
    float* Y1f  = Gf   + 131072;         // 131072
    float* Y2f  = Y1f  + 131072;         // 131072
    float* Y3f  = Y2f  + 131072;         // 131072
    float* Sf   = Y3f  + 131072;         // 131072
    float* dlt1 = Sf   + 131072;         // 1024
    float* dlt2 = dlt1 + 1024;           // 1024
    unsigned short* Lb    = (unsigned short*)(dlt2 + 1024);
    unsigned short* dLb   = Lb    + 1048576;
    unsigned short* LbT   = dLb   + 1048576;
    unsigned short* dLbT  = LbT   + 1048576;
    unsigned short* P1b   = dLbT  + 1048576;
    unsigned short* P2b   = P1b   + 1048576;
    unsigned short* VUt   = P2b   + 1048576;                    // 262144 [V|U]^T
    unsigned short* GTt   = VUt   + 262144;                     // 262144 [G|T]^T
    unsigned short* Xb    = GTt   + 262144;                     // 196608 [1024][192]
    unsigned short* WtT   = Xb    + 196608;                     // 24576
    unsigned short* WB1T  = WtT   + 24576;                      // 16384
    unsigned short* WB2T  = WB1T  + 16384;                      // 16384
    unsigned short* xnb   = WB2T  + 16384;                      // 131072

    conv_all<<<dim3(3552), dim3(256), 0, stream>>>(
        L, dL, x_sub, names, src, dst, W_tune, W_B1, W_B2,
        Lb, dLb, LbT, dLbT, Xb, WtT, WB1T, WB2T);

    gemm_p12<<<dim3(32, 16), dim3(256), 0, stream>>>(LbT, dLbT, dLb, P1b, P2b);

    gemm_zt<<<dim3(2, 16), dim3(256), 0, stream>>>(Xb, WtT, b_tune, zt);

    // ---- stage 1 ----
    rms_dt<<<dim3(1024), dim3(128), 0, stream>>>(
        zt, rms1, W_dt, b_dt, A1, m1, act, xnb, VU, VUt, dlt1);
    gemm_bz2<<<dim3(2, 16), dim3(256), 0, stream>>>(xnb, WB1T, b_B1, dlt1, VU, VUt);
    gemm_ga<<<dim3(4, 32), dim3(256), 0, stream>>>(Lb, dLb, VUt, VU, GTt, Gf);
    gemm_gb<<<dim3(8, 16), dim3(256), 0, stream>>>(dLb, P1b, P2b, GTt, Y1f, Y2f, Y3f, Sf);

    // ---- stage 2 ----
    ew_mid2<<<dim3(1024), dim3(128), 0, stream>>>(
        Y1f, Y2f, Y3f, Sf, Gf, zt, dlt1, A1,
        rms2, W_dt, b_dt, A2, m2, act,
        xnb, VU, VUt, dlt2, out);
    gemm_bz2<<<dim3(2, 16), dim3(256), 0, stream>>>(xnb, WB2T, b_B2, dlt2, VU, VUt);
    gemm_ga<<<dim3(4, 32), dim3(256), 0, stream>>>(Lb, dLb, VUt, VU, GTt, Gf);
    gemm_gb<<<dim3(8, 16), dim3(256), 0, stream>>>(dLb, P1b, P2b, GTt, Y1f, Y2f, Y3f, Sf);

    ew_tail<<<dim3(512), dim3(256), 0, stream>>>(
        Y1f, Y2f, Y3f, Sf, Gf, VU, dlt2, A2, out + 131072);
}